// Round 9
// baseline (17093.587 us; speedup 1.0000x reference)
//
#include <hip/hip_runtime.h>
#include <stdint.h>

#define SEQ   2048
#define BATCH 128
#define DIN   256
#define DH    512
#define DOUT  256

typedef uint16_t u16;
typedef uint32_t u32;
typedef __attribute__((ext_vector_type(8))) short short8;
typedef __attribute__((ext_vector_type(4))) float f32x4;

__device__ __forceinline__ u16 f2bf(float f) {
    u32 u = __float_as_uint(f);
    u += 0x7fffu + ((u >> 16) & 1u);   // RNE
    return (u16)(u >> 16);
}
__device__ __forceinline__ float bf2f(u16 h) {
    return __uint_as_float(((u32)h) << 16);
}
__device__ __forceinline__ float tanh_fast(float x) {
    float e = __expf(2.0f * x);                       // inf for large x -> rcp=0 -> 1
    return 1.0f - 2.0f * __builtin_amdgcn_rcpf(e + 1.0f);
}

// xp layout: value = xp[t][batch = bb*16 + g4*4 + r][hcol = cidx*16 + c],
// cidx = hcol>>4 (0..31), the 4 r-values consecutive u16 (one uint2).
__device__ __forceinline__ size_t xpidx(int t, int bb, int cidx, int g4, int c) {
    return (((((size_t)t * 8 + bb) * 32 + cidx) * 4 + g4) * 16 + c) * 4;
}

// ---------------------------------------------------------------------------
// Pack W_hh (fp32 [512 n][512 k]) into per-slice MFMA fragment order (bf16):
// Wp[(s*16+kc)*512 + lane*8 + j] = W[s*16+(lane&15)][kc*32+(lane>>4)*8+j]
// s = col slice 0..31 (16 cols each), kc 0..15.
// ---------------------------------------------------------------------------
__global__ void pack_whh_kernel(const float* __restrict__ W, u16* __restrict__ Wp) {
    int idx  = blockIdx.x * 256 + threadIdx.x;    // 0..32767
    int lane = idx & 63;
    int kc   = (idx >> 6) & 15;
    int s    = idx >> 10;                          // 0..31
    int col = s * 16 + (lane & 15);
    int k0  = kc * 32 + (lane >> 4) * 8;
    short8 v;
#pragma unroll
    for (int j = 0; j < 8; ++j) v[j] = (short)f2bf(W[(size_t)col * DH + k0 + j]);
    *reinterpret_cast<short8*>(Wp + (size_t)idx * 8) = v;
}

// ---------------------------------------------------------------------------
// Phase 1: xp = x @ W_ih^T + b_ih + b_hh, bf16, written in xpidx layout.
// M=262144, N=512, K=256.  Tile: 128(M) x 256(N), BK=64, 8 waves.
// ---------------------------------------------------------------------------
__global__ __launch_bounds__(512) void xproj_kernel(
    const float* __restrict__ x, const float* __restrict__ W_ih,
    const float* __restrict__ b_ih, const float* __restrict__ b_hh,
    u16* __restrict__ xp) {
    __shared__ u16 As[128 * 64];
    __shared__ u16 Bs[256 * 64];
    const int tid  = threadIdx.x;
    const int lane = tid & 63;
    const int wid  = tid >> 6;     // 0..7
    const int wm   = wid >> 2;     // 0..1
    const int wn   = wid & 3;      // 0..3
    const int mt   = blockIdx.x;   // 0..2047
    const int nt   = blockIdx.y;   // 0..1

    f32x4 acc[4][4];
#pragma unroll
    for (int i = 0; i < 4; ++i)
#pragma unroll
        for (int j = 0; j < 4; ++j) acc[i][j] = (f32x4){0.f, 0.f, 0.f, 0.f};

    for (int kk = 0; kk < DIN; kk += 64) {
        __syncthreads();
        {   // stage A: 128 rows x 64 k (fp32 -> bf16), 16 elems/thread
            int r = tid >> 2, q = tid & 3;
            const float4* gp = (const float4*)(x + (size_t)(mt * 128 + r) * DIN + kk + q * 16);
            float4 v0 = gp[0], v1 = gp[1], v2 = gp[2], v3 = gp[3];
            short8 h0, h1;
            h0[0]=(short)f2bf(v0.x); h0[1]=(short)f2bf(v0.y); h0[2]=(short)f2bf(v0.z); h0[3]=(short)f2bf(v0.w);
            h0[4]=(short)f2bf(v1.x); h0[5]=(short)f2bf(v1.y); h0[6]=(short)f2bf(v1.z); h0[7]=(short)f2bf(v1.w);
            h1[0]=(short)f2bf(v2.x); h1[1]=(short)f2bf(v2.y); h1[2]=(short)f2bf(v2.z); h1[3]=(short)f2bf(v2.w);
            h1[4]=(short)f2bf(v3.x); h1[5]=(short)f2bf(v3.y); h1[6]=(short)f2bf(v3.z); h1[7]=(short)f2bf(v3.w);
            int base = r * 64, sw = (r & 7) << 3, ke = q * 16;
            *(short8*)&As[base + (ke ^ sw)]       = h0;
            *(short8*)&As[base + ((ke + 8) ^ sw)] = h1;
        }
        {   // stage B: 256 rows x 64 k, 32 elems/thread
            int r = tid >> 1, hf = tid & 1;
            const float4* gp = (const float4*)(W_ih + (size_t)(nt * 256 + r) * DIN + kk + hf * 32);
            int base = r * 64, sw = (r & 7) << 3;
#pragma unroll
            for (int cp = 0; cp < 2; ++cp) {
                float4 u0 = gp[cp*4+0], u1 = gp[cp*4+1], u2 = gp[cp*4+2], u3 = gp[cp*4+3];
                short8 t0, t1;
                t0[0]=(short)f2bf(u0.x); t0[1]=(short)f2bf(u0.y); t0[2]=(short)f2bf(u0.z); t0[3]=(short)f2bf(u0.w);
                t0[4]=(short)f2bf(u1.x); t0[5]=(short)f2bf(u1.y); t0[6]=(short)f2bf(u1.z); t0[7]=(short)f2bf(u1.w);
                t1[0]=(short)f2bf(u2.x); t1[1]=(short)f2bf(u2.y); t1[2]=(short)f2bf(u2.z); t1[3]=(short)f2bf(u2.w);
                t1[4]=(short)f2bf(u3.x); t1[5]=(short)f2bf(u3.y); t1[6]=(short)f2bf(u3.z); t1[7]=(short)f2bf(u3.w);
                int ke = hf * 32 + cp * 16;
                *(short8*)&Bs[base + (ke ^ sw)]       = t0;
                *(short8*)&Bs[base + ((ke + 8) ^ sw)] = t1;
            }
        }
        __syncthreads();
#pragma unroll
        for (int kt = 0; kt < 2; ++kt) {
            short8 a[4], b[4];
            int ke = kt * 32 + (lane >> 4) * 8;
#pragma unroll
            for (int mi = 0; mi < 4; ++mi) {
                int rr = wm * 64 + mi * 16 + (lane & 15);
                a[mi] = *(const short8*)&As[rr * 64 + (ke ^ ((rr & 7) << 3))];
            }
#pragma unroll
            for (int ni = 0; ni < 4; ++ni) {
                int rr = wn * 64 + ni * 16 + (lane & 15);
                b[ni] = *(const short8*)&Bs[rr * 64 + (ke ^ ((rr & 7) << 3))];
            }
#pragma unroll
            for (int mi = 0; mi < 4; ++mi)
#pragma unroll
                for (int ni = 0; ni < 4; ++ni)
                    acc[mi][ni] = __builtin_amdgcn_mfma_f32_16x16x32_bf16(a[mi], b[ni], acc[mi][ni], 0, 0, 0);
        }
    }
    // epilogue -> xpidx layout. t = mt, bb = wm*4+mi, cidx = (nt*4+wn)*4+ni.
    int g4 = lane >> 4, c = lane & 15;
#pragma unroll
    for (int ni = 0; ni < 4; ++ni) {
        int col = nt * 256 + wn * 64 + ni * 16 + c;
        float bias = b_ih[col] + b_hh[col];
#pragma unroll
        for (int mi = 0; mi < 4; ++mi) {
            u32 lo = (u32)f2bf(acc[mi][ni][0] + bias) | ((u32)f2bf(acc[mi][ni][1] + bias) << 16);
            u32 hi = (u32)f2bf(acc[mi][ni][2] + bias) | ((u32)f2bf(acc[mi][ni][3] + bias) << 16);
            uint2 v; v.x = lo; v.y = hi;
            *reinterpret_cast<uint2*>(xp + xpidx(mt, wm * 4 + mi, (nt * 4 + wn) * 4 + ni, g4, c)) = v;
        }
    }
}

// ---------------------------------------------------------------------------
// Phase 2: recurrence. 32 blocks = 8 batch-groups (bg) x 4 col-groups (cg),
// 512 thr (8 waves). Wave owns 16 H-cols -> W = 16 frags = 64 VGPRs, which
// fits INSIDE the ~128-reg bin the allocator insists on (r2..r8 lesson: it
// NEVER grants more; make the demand fit instead of fighting). ALL of W_hh
// is register-resident GPU-wide; per-step W traffic = 0.
// Per step, the 4 cg-blocks of a bg exchange h slices through L2:
//   write own slice -> threadfence -> barrier -> release-store flag ->
//   poll partner flags -> barrier -> acquire fence -> read 3 slices.
// bg = blockIdx&7 so a group's 4 blocks share an XCD under round-robin.
// Parity-reuse safety: a block enters iter t+2 only after all partners
// published t+2, which orders all buffer reuse (proof in journal).
// ---------------------------------------------------------------------------
__global__ __launch_bounds__(512) void rnn_rec_kernel(
    const u16* __restrict__ xp, const u16* __restrict__ Wp,
    u16* __restrict__ h_pub, u16* __restrict__ h_last,
    int* flags) {
    __shared__ u16 h_s[2][16 * 512];     // 32 KB h double buffer
    __shared__ u16 lds_pad[20480];       // 40 KB occupancy limiter (<=2 blk/CU)
    const int tid = threadIdx.x, lane = tid & 63, wv = tid >> 6;  // wv 0..7
    const int bg = blockIdx.x & 7, cg = blockIdx.x >> 3;          // cg 0..3
    const int s = cg * 8 + wv;                                    // slice 0..31
    const int g4 = lane >> 4, c = lane & 15;
    const int arow = lane & 15;
    const int asw = (arow & 7) << 3;

    if (blockIdx.x >= 1000) lds_pad[tid] = 0;   // never true; keeps pad alive

    // W slice (16 cols x 512 k) into registers: 16 frags = 64 VGPRs.
    short8 wr[16];
#pragma unroll
    for (int kc = 0; kc < 16; ++kc)
        wr[kc] = *(const short8*)(Wp + ((size_t)(s * 16 + kc)) * 512 + lane * 8);

    // h(0) = 0
    *(short8*)&h_s[0][tid * 16]     = (short8)0;
    *(short8*)&h_s[0][tid * 16 + 8] = (short8)0;

    // prefetch xp(0)
    uint2 xn = *(const uint2*)(xp + xpidx(0, bg, s, g4, c));

    __syncthreads();

    for (int t = 0; t < SEQ; ++t) {
        const int cur = t & 1, nxt = cur ^ 1;
        uint2 xc = xn;
        if (t + 1 < SEQ)
            xn = *(const uint2*)(xp + xpidx(t + 1, bg, s, g4, c));

        // two interleaved MFMA chains for ILP; accA seeded with xp(t)
        f32x4 accA, accB;
        accA[0] = __uint_as_float(xc.x << 16);
        accA[1] = __uint_as_float(xc.x & 0xffff0000u);
        accA[2] = __uint_as_float(xc.y << 16);
        accA[3] = __uint_as_float(xc.y & 0xffff0000u);
        accB = (f32x4){0.f, 0.f, 0.f, 0.f};
#pragma unroll
        for (int kc = 0; kc < 8; ++kc) {
            short8 a0 = *(const short8*)&h_s[cur][arow * 512 + ((kc * 32 + g4 * 8) ^ asw)];
            short8 a1 = *(const short8*)&h_s[cur][arow * 512 + (((kc + 8) * 32 + g4 * 8) ^ asw)];
            accA = __builtin_amdgcn_mfma_f32_16x16x32_bf16(a0, wr[kc], accA, 0, 0, 0);
            accB = __builtin_amdgcn_mfma_f32_16x16x32_bf16(a1, wr[kc + 8], accB, 0, 0, 0);
        }

        // epilogue: row = 4*g4+r (batch row), col = s*16 + c
        const int colL = s * 16 + c;
        const size_t pb = ((size_t)(nxt * 8 + bg) * 4 + cg) * 2048;  // h_pub slice
#pragma unroll
        for (int r = 0; r < 4; ++r) {
            int row = 4 * g4 + r;
            u16 hv = f2bf(tanh_fast(accA[r] + accB[r]));
            h_s[nxt][row * 512 + (colL ^ ((row & 7) << 3))] = hv;
            if (t == SEQ - 1)
                h_last[(size_t)(bg * 16 + row) * DH + colL] = hv;
            else
                h_pub[pb + row * 128 + (colL - cg * 128)] = hv;
        }

        if (t == SEQ - 1) break;   // uniform; no exchange after last step

        __threadfence();           // own h_pub stores visible at device scope
        __syncthreads();           // all waves' stores fenced
        if (tid == 0)
            __hip_atomic_store(&flags[bg * 4 + cg], t + 1,
                               __ATOMIC_RELEASE, __HIP_MEMORY_SCOPE_AGENT);
        if (tid < 4) {             // lanes 0..3 of wave 0 poll the 4 flags
            while (__hip_atomic_load(&flags[bg * 4 + tid],
                                     __ATOMIC_RELAXED, __HIP_MEMORY_SCOPE_AGENT) <= t)
                __builtin_amdgcn_s_sleep(1);
        }
        __syncthreads();
        __builtin_amdgcn_fence(__ATOMIC_ACQUIRE, "agent");  // invalidate L1

        // stage the 3 foreign slices (4 KB each) into h_s[nxt]
        {
            const int row = tid >> 5, q = tid & 31;
            const int rsw = (row & 7) << 3;
            const size_t fb = (size_t)(nxt * 8 + bg) * 4 * 2048;
#pragma unroll
            for (int sc = 0; sc < 4; ++sc) {
                if (sc == cg) continue;
                uint2 v = *(const uint2*)&h_pub[fb + (size_t)sc * 2048 + row * 128 + q * 4];
                int col = sc * 128 + q * 4;
                *(uint2*)&h_s[nxt][row * 512 + (col ^ rsw)] = v;
            }
        }
        __syncthreads();
    }
}

// ---------------------------------------------------------------------------
// Phase 3: out[b][o] = h_last[b,:]·W_fc[o,:] + b_fc[o]   (fp32 VALU, tiny)
// ---------------------------------------------------------------------------
__global__ __launch_bounds__(256) void fc_kernel(
    const u16* __restrict__ h_last, const float* __restrict__ W_fc,
    const float* __restrict__ b_fc, float* __restrict__ out) {
    __shared__ float hsh[DH];
    int b = blockIdx.x, o = threadIdx.x;
    for (int i = threadIdx.x; i < DH; i += 256) hsh[i] = bf2f(h_last[(size_t)b * DH + i]);
    __syncthreads();
    const float* w = W_fc + (size_t)o * DH;
    float s = 0.f;
#pragma unroll 8
    for (int k = 0; k < DH; ++k) s += hsh[k] * w[k];
    out[(size_t)b * DOUT + o] = s + b_fc[o];
}

extern "C" void kernel_launch(void* const* d_in, const int* in_sizes, int n_in,
                              void* d_out, int out_size, void* d_ws, size_t ws_size,
                              hipStream_t stream) {
    const float* x    = (const float*)d_in[0];
    const float* W_ih = (const float*)d_in[1];
    const float* W_hh = (const float*)d_in[2];
    const float* b_ih = (const float*)d_in[3];
    const float* b_hh = (const float*)d_in[4];
    const float* W_fc = (const float*)d_in[5];
    const float* b_fc = (const float*)d_in[6];
    float* out = (float*)d_out;

    u16* xp     = (u16*)d_ws;                               // 256 MB
    u16* Wp     = xp + (size_t)SEQ * BATCH * DH;            // 512 KB
    u16* h_pub  = Wp + (size_t)32 * 16 * 512;               // 256 KB (2 par x 8 bg x 4 cg x 16 x 128)
    u16* h_last = h_pub + (size_t)2 * 8 * 4 * 16 * 128;     // 128 KB
    int* flags  = (int*)(h_last + (size_t)BATCH * DH);      // 128 B

    hipMemsetAsync(flags, 0, 32 * sizeof(int), stream);     // re-zero every call
    hipLaunchKernelGGL(pack_whh_kernel, dim3(128), dim3(256), 0, stream, W_hh, Wp);
    hipLaunchKernelGGL(xproj_kernel, dim3(2048, 2), dim3(512), 0, stream, x, W_ih, b_ih, b_hh, xp);
    hipLaunchKernelGGL(rnn_rec_kernel, dim3(32), dim3(512), 0, stream, xp, Wp, h_pub, h_last, flags);
    hipLaunchKernelGGL(fc_kernel, dim3(128), dim3(256), 0, stream, h_last, W_fc, b_fc, out);
}

// Round 10
// 4616.469 us; speedup vs baseline: 3.7027x; 3.7027x over previous
//
#include <hip/hip_runtime.h>
#include <stdint.h>

#define SEQ   2048
#define BATCH 128
#define DIN   256
#define DH    512
#define DOUT  256

typedef uint16_t u16;
typedef uint32_t u32;
typedef __attribute__((ext_vector_type(8))) short short8;
typedef __attribute__((ext_vector_type(4))) float f32x4;
typedef __attribute__((ext_vector_type(4))) int i32x4;

__device__ __forceinline__ u16 f2bf(float f) {
    u32 u = __float_as_uint(f);
    u += 0x7fffu + ((u >> 16) & 1u);   // RNE
    return (u16)(u >> 16);
}
__device__ __forceinline__ float bf2f(u16 h) {
    return __uint_as_float(((u32)h) << 16);
}
__device__ __forceinline__ float tanh_fast(float x) {
    float e = __expf(2.0f * x);                       // inf for large x -> rcp=0 -> 1
    return 1.0f - 2.0f * __builtin_amdgcn_rcpf(e + 1.0f);
}

// ---------------------------------------------------------------------------
// Pass A: max|W_hh| (for the int8 scale). 256 blocks x 256 thr x 4 elems.
// ---------------------------------------------------------------------------
__global__ __launch_bounds__(256) void wmax_kernel(const float* __restrict__ W,
                                                   unsigned* __restrict__ wmax) {
    __shared__ float red[256];
    int idx = blockIdx.x * 256 + threadIdx.x;
    float m = 0.f;
#pragma unroll
    for (int j = 0; j < 4; ++j) m = fmaxf(m, fabsf(W[(size_t)idx * 4 + j]));
    red[threadIdx.x] = m;
    __syncthreads();
    for (int s = 128; s > 0; s >>= 1) {
        if (threadIdx.x < s) red[threadIdx.x] = fmaxf(red[threadIdx.x], red[threadIdx.x + s]);
        __syncthreads();
    }
    if (threadIdx.x == 0) atomicMax(wmax, __float_as_uint(red[0]));  // floats >=0: uint order
}

// ---------------------------------------------------------------------------
// Pass B: pack W_hh into int8 MFMA-A-operand fragments.
// Wq[((wv*8+kc)*4+n)*1024 + lane*16 + j] =
//     rint( W[wv*64+n*16+(lane&15)][kc*64+(lane>>4)*16+j] * 127/wmax )
// (16x16x64 i8 A-frag: lane holds row l&15, k = (l>>4)*16 + 0..15.)
// ---------------------------------------------------------------------------
__global__ __launch_bounds__(256) void pack_whh_i8_kernel(
    const float* __restrict__ W, const unsigned* __restrict__ wmax,
    char* __restrict__ Wq) {
    int idx  = blockIdx.x * 256 + threadIdx.x;     // 0..16383
    int lane = idx & 63;
    int n    = (idx >> 6) & 3;
    int kc   = (idx >> 8) & 7;
    int wv   = idx >> 11;                           // 0..7
    float s = 127.0f / __uint_as_float(*wmax);
    int col = wv * 64 + n * 16 + (lane & 15);
    int k0  = kc * 64 + (lane >> 4) * 16;
    char q[16];
#pragma unroll
    for (int j = 0; j < 16; ++j)
        q[j] = (char)(int)rintf(W[(size_t)col * DH + k0 + j] * s);
    *reinterpret_cast<i32x4*>(Wq + (size_t)idx * 16) = *reinterpret_cast<i32x4*>(q);
}

// ---------------------------------------------------------------------------
// Phase 1: xp = x @ W_ih^T + b_ih + b_hh, bf16. SWAPPED-OPERAND MFMA:
// D = mfma(W_ih_frag, x_frag) so each lane holds 4 CONSECUTIVE cols of one
// batch row -> fully coalesced uint2 stores in the transposed xp2 layout:
// slot(t, bb, cidx, lane) holds batch bb*16+(lane&15),
// cols cidx*16 + (lane>>4)*4 + 0..3 as 4 consecutive bf16.
// ---------------------------------------------------------------------------
__global__ __launch_bounds__(512) void xproj_kernel(
    const float* __restrict__ x, const float* __restrict__ W_ih,
    const float* __restrict__ b_ih, const float* __restrict__ b_hh,
    u16* __restrict__ xp) {
    __shared__ u16 As[128 * 64];
    __shared__ u16 Bs[256 * 64];
    const int tid  = threadIdx.x;
    const int lane = tid & 63;
    const int wid  = tid >> 6;     // 0..7
    const int wm   = wid >> 2;     // 0..1
    const int wn   = wid & 3;      // 0..3
    const int mt   = blockIdx.x;   // 0..2047
    const int nt   = blockIdx.y;   // 0..1

    f32x4 acc[4][4];
#pragma unroll
    for (int i = 0; i < 4; ++i)
#pragma unroll
        for (int j = 0; j < 4; ++j) acc[i][j] = (f32x4){0.f, 0.f, 0.f, 0.f};

    for (int kk = 0; kk < DIN; kk += 64) {
        __syncthreads();
        {   // stage A: 128 rows x 64 k (fp32 -> bf16), 16 elems/thread
            int r = tid >> 2, q = tid & 3;
            const float4* gp = (const float4*)(x + (size_t)(mt * 128 + r) * DIN + kk + q * 16);
            float4 v0 = gp[0], v1 = gp[1], v2 = gp[2], v3 = gp[3];
            short8 h0, h1;
            h0[0]=(short)f2bf(v0.x); h0[1]=(short)f2bf(v0.y); h0[2]=(short)f2bf(v0.z); h0[3]=(short)f2bf(v0.w);
            h0[4]=(short)f2bf(v1.x); h0[5]=(short)f2bf(v1.y); h0[6]=(short)f2bf(v1.z); h0[7]=(short)f2bf(v1.w);
            h1[0]=(short)f2bf(v2.x); h1[1]=(short)f2bf(v2.y); h1[2]=(short)f2bf(v2.z); h1[3]=(short)f2bf(v2.w);
            h1[4]=(short)f2bf(v3.x); h1[5]=(short)f2bf(v3.y); h1[6]=(short)f2bf(v3.z); h1[7]=(short)f2bf(v3.w);
            int base = r * 64, sw = (r & 7) << 3, ke = q * 16;
            *(short8*)&As[base + (ke ^ sw)]       = h0;
            *(short8*)&As[base + ((ke + 8) ^ sw)] = h1;
        }
        {   // stage B: 256 rows x 64 k, 32 elems/thread
            int r = tid >> 1, hf = tid & 1;
            const float4* gp = (const float4*)(W_ih + (size_t)(nt * 256 + r) * DIN + kk + hf * 32);
            int base = r * 64, sw = (r & 7) << 3;
#pragma unroll
            for (int cp = 0; cp < 2; ++cp) {
                float4 u0 = gp[cp*4+0], u1 = gp[cp*4+1], u2 = gp[cp*4+2], u3 = gp[cp*4+3];
                short8 t0, t1;
                t0[0]=(short)f2bf(u0.x); t0[1]=(short)f2bf(u0.y); t0[2]=(short)f2bf(u0.z); t0[3]=(short)f2bf(u0.w);
                t0[4]=(short)f2bf(u1.x); t0[5]=(short)f2bf(u1.y); t0[6]=(short)f2bf(u1.z); t0[7]=(short)f2bf(u1.w);
                t1[0]=(short)f2bf(u2.x); t1[1]=(short)f2bf(u2.y); t1[2]=(short)f2bf(u2.z); t1[3]=(short)f2bf(u2.w);
                t1[4]=(short)f2bf(u3.x); t1[5]=(short)f2bf(u3.y); t1[6]=(short)f2bf(u3.z); t1[7]=(short)f2bf(u3.w);
                int ke = hf * 32 + cp * 16;
                *(short8*)&Bs[base + (ke ^ sw)]       = t0;
                *(short8*)&Bs[base + ((ke + 8) ^ sw)] = t1;
            }
        }
        __syncthreads();
#pragma unroll
        for (int kt = 0; kt < 2; ++kt) {
            short8 a[4], b[4];
            int ke = kt * 32 + (lane >> 4) * 8;
#pragma unroll
            for (int mi = 0; mi < 4; ++mi) {
                int rr = wm * 64 + mi * 16 + (lane & 15);
                a[mi] = *(const short8*)&As[rr * 64 + (ke ^ ((rr & 7) << 3))];
            }
#pragma unroll
            for (int ni = 0; ni < 4; ++ni) {
                int rr = wn * 64 + ni * 16 + (lane & 15);
                b[ni] = *(const short8*)&Bs[rr * 64 + (ke ^ ((rr & 7) << 3))];
            }
            // SWAPPED: A-operand = W_ih frag, B-operand = x frag.
#pragma unroll
            for (int mi = 0; mi < 4; ++mi)
#pragma unroll
                for (int ni = 0; ni < 4; ++ni)
                    acc[mi][ni] = __builtin_amdgcn_mfma_f32_16x16x32_bf16(b[ni], a[mi], acc[mi][ni], 0, 0, 0);
        }
    }
    // epilogue: D row = W col = ni*16 + (lane>>4)*4 + r; D col = batch&15 = lane&15.
    const int lq = lane >> 4;
#pragma unroll
    for (int ni = 0; ni < 4; ++ni) {
        int col0 = nt * 256 + wn * 64 + ni * 16 + lq * 4;
        float4 bi = *(const float4*)(b_ih + col0);
        float4 bh = *(const float4*)(b_hh + col0);
        float bb0 = bi.x + bh.x, bb1 = bi.y + bh.y, bb2 = bi.z + bh.z, bb3 = bi.w + bh.w;
#pragma unroll
        for (int mi = 0; mi < 4; ++mi) {
            float v0 = acc[mi][ni][0] + bb0;
            float v1 = acc[mi][ni][1] + bb1;
            float v2 = acc[mi][ni][2] + bb2;
            float v3 = acc[mi][ni][3] + bb3;
            uint2 v;
            v.x = (u32)f2bf(v0) | ((u32)f2bf(v1) << 16);
            v.y = (u32)f2bf(v2) | ((u32)f2bf(v3) << 16);
            int bbk = wm * 4 + mi;
            int cidx = (nt * 4 + wn) * 4 + ni;
            *(uint2*)(xp + ((((size_t)mt * 8 + bbk) * 32 + cidx) * 64 + lane) * 4) = v;
        }
    }
}

// ---------------------------------------------------------------------------
// Phase 2: recurrence, int8. 8 blocks x 512 thr (8 waves, 2/SIMD), 1 blk/CU.
// r2..r9 lesson: W residency in regs is unwinnable; the wall is the per-CU
// L2 pipe (~60 B/cyc). int8 halves W to 256 KB: chunks 0..3 in LDS (128 KB),
// 4..5 reg-attempt (64 regs; if remat'ed they just join the stream), 6..7
// streamed. Swapped MFMA (W as A-operand): lane owns batch row lane&15 and
// 4 consecutive cols -> b32 h-writes, coalesced xp, ~2-way LDS conflicts.
// acc is exact i32; pre = acc * (wmax/127^2) + xp(bf16); h re-quantized to
// int8 (scale 127) for the next step; h_last written bf16 at t=SEQ-1.
// ---------------------------------------------------------------------------
__global__ __launch_bounds__(512) void rnn_rec_kernel(
    const u16* __restrict__ xp, const char* __restrict__ Wq,
    const unsigned* __restrict__ wmax_p, u16* __restrict__ h_last) {
    __shared__ char W_lds[131072];        // 128 KB : chunks 0..3
    __shared__ char h_s[2][16 * 512];     // 16 KB  : int8 h double buffer
    const int tid = threadIdx.x, lane = tid & 63, wv = tid >> 6;  // wv 0..7
    const int bg = blockIdx.x;
    const int row = lane & 15, lq = lane >> 4;
    const int sw = (row & 7) << 4;
    const float sc = __uint_as_float(*wmax_p) * (1.0f / (127.f * 127.f));

    // stage W chunks 0..3 into LDS (each wave its own 16 KB slice)
#pragma unroll
    for (int f = 0; f < 16; ++f) {
        int kc = f >> 2, n = f & 3;
        i32x4 v = *(const i32x4*)(Wq + (size_t)((wv * 8 + kc) * 4 + n) * 1024 + lane * 16);
        *(i32x4*)&W_lds[((wv * 4 + kc) * 4 + n) * 1024 + lane * 16] = v;
    }
    // chunks 4,5 -> registers (best effort; remat == streaming, both fine)
    i32x4 wr4[4], wr5[4];
#pragma unroll
    for (int n = 0; n < 4; ++n) {
        wr4[n] = *(const i32x4*)(Wq + (size_t)((wv * 8 + 4) * 4 + n) * 1024 + lane * 16);
        wr5[n] = *(const i32x4*)(Wq + (size_t)((wv * 8 + 5) * 4 + n) * 1024 + lane * 16);
    }
    const char* wps_base = Wq + (size_t)((wv * 8 + 6) * 4) * 1024 + lane * 16;

    // h(0) = 0
    *(i32x4*)&h_s[0][tid * 32]      = (i32x4){0, 0, 0, 0};
    *(i32x4*)&h_s[0][tid * 32 + 16] = (i32x4){0, 0, 0, 0};

    // prefetch xp(0): cidx = wv*4 + n
    uint2 xn[4];
#pragma unroll
    for (int n = 0; n < 4; ++n)
        xn[n] = *(const uint2*)(xp + ((((size_t)0 * 8 + bg) * 32 + (wv * 4 + n)) * 64 + lane) * 4);

    __syncthreads();

    for (int t = 0; t < SEQ; ++t) {
        const int cur = t & 1, nxt = cur ^ 1;

        // streamed chunks 6,7 (pointer re-defined per-iter: blocks LICM hoist)
        const char* wps = wps_base;
        asm volatile("" : "+v"(wps));
        i32x4 s6[4], s7[4];
#pragma unroll
        for (int n = 0; n < 4; ++n) s6[n] = *(const i32x4*)(wps + n * 1024);
#pragma unroll
        for (int n = 0; n < 4; ++n) s7[n] = *(const i32x4*)(wps + 4096 + n * 1024);

        uint2 xc[4];
#pragma unroll
        for (int n = 0; n < 4; ++n) xc[n] = xn[n];
        if (t + 1 < SEQ) {
#pragma unroll
            for (int n = 0; n < 4; ++n)
                xn[n] = *(const uint2*)(xp + ((((size_t)(t + 1) * 8 + bg) * 32 + (wv * 4 + n)) * 64 + lane) * 4);
        }

        i32x4 acc[4];
#pragma unroll
        for (int n = 0; n < 4; ++n) acc[n] = (i32x4){0, 0, 0, 0};

        // chunks 0..3 : W from LDS
#pragma unroll
        for (int kc = 0; kc < 4; ++kc) {
            i32x4 hf = *(const i32x4*)&h_s[cur][row * 512 + ((kc * 64 + lq * 16) ^ sw)];
#pragma unroll
            for (int n = 0; n < 4; ++n) {
                i32x4 wf = *(const i32x4*)&W_lds[((wv * 4 + kc) * 4 + n) * 1024 + lane * 16];
                acc[n] = __builtin_amdgcn_mfma_i32_16x16x64_i8(wf, hf, acc[n], 0, 0, 0);
            }
        }
        // chunks 4,5 : W from registers
        {
            i32x4 hf = *(const i32x4*)&h_s[cur][row * 512 + ((4 * 64 + lq * 16) ^ sw)];
#pragma unroll
            for (int n = 0; n < 4; ++n)
                acc[n] = __builtin_amdgcn_mfma_i32_16x16x64_i8(wr4[n], hf, acc[n], 0, 0, 0);
        }
        {
            i32x4 hf = *(const i32x4*)&h_s[cur][row * 512 + ((5 * 64 + lq * 16) ^ sw)];
#pragma unroll
            for (int n = 0; n < 4; ++n)
                acc[n] = __builtin_amdgcn_mfma_i32_16x16x64_i8(wr5[n], hf, acc[n], 0, 0, 0);
        }
        // chunks 6,7 : W streamed from L2
        {
            i32x4 hf = *(const i32x4*)&h_s[cur][row * 512 + ((6 * 64 + lq * 16) ^ sw)];
#pragma unroll
            for (int n = 0; n < 4; ++n)
                acc[n] = __builtin_amdgcn_mfma_i32_16x16x64_i8(s6[n], hf, acc[n], 0, 0, 0);
        }
        {
            i32x4 hf = *(const i32x4*)&h_s[cur][row * 512 + ((7 * 64 + lq * 16) ^ sw)];
#pragma unroll
            for (int n = 0; n < 4; ++n)
                acc[n] = __builtin_amdgcn_mfma_i32_16x16x64_i8(s7[n], hf, acc[n], 0, 0, 0);
        }

        // epilogue: lane = (batch row = lane&15, cols colb..colb+3)
#pragma unroll
        for (int n = 0; n < 4; ++n) {
            float p0 = (float)acc[n][0] * sc + bf2f((u16)(xc[n].x & 0xffffu));
            float p1 = (float)acc[n][1] * sc + bf2f((u16)(xc[n].x >> 16));
            float p2 = (float)acc[n][2] * sc + bf2f((u16)(xc[n].y & 0xffffu));
            float p3 = (float)acc[n][3] * sc + bf2f((u16)(xc[n].y >> 16));
            float h0 = tanh_fast(p0), h1 = tanh_fast(p1);
            float h2 = tanh_fast(p2), h3 = tanh_fast(p3);
            int colb = wv * 64 + n * 16 + lq * 4;
            if (t == SEQ - 1) {
                uint2 hv;
                hv.x = (u32)f2bf(h0) | ((u32)f2bf(h1) << 16);
                hv.y = (u32)f2bf(h2) | ((u32)f2bf(h3) << 16);
                *(uint2*)(h_last + (size_t)(bg * 16 + row) * DH + colb) = hv;
            } else {
                int q0 = (int)rintf(h0 * 127.f), q1 = (int)rintf(h1 * 127.f);
                int q2 = (int)rintf(h2 * 127.f), q3 = (int)rintf(h3 * 127.f);
                u32 pk = (u32)(q0 & 255) | ((u32)(q1 & 255) << 8) |
                         ((u32)(q2 & 255) << 16) | ((u32)(q3 & 255) << 24);
                *(u32*)&h_s[nxt][row * 512 + (colb ^ sw)] = pk;
            }
        }
        if (t == SEQ - 1) break;
        __syncthreads();
    }
}

// ---------------------------------------------------------------------------
// Phase 3: out[b][o] = h_last[b,:]·W_fc[o,:] + b_fc[o]   (fp32 VALU, tiny)
// ---------------------------------------------------------------------------
__global__ __launch_bounds__(256) void fc_kernel(
    const u16* __restrict__ h_last, const float* __restrict__ W_fc,
    const float* __restrict__ b_fc, float* __restrict__ out) {
    __shared__ float hsh[DH];
    int b = blockIdx.x, o = threadIdx.x;
    for (int i = threadIdx.x; i < DH; i += 256) hsh[i] = bf2f(h_last[(size_t)b * DH + i]);
    __syncthreads();
    const float* w = W_fc + (size_t)o * DH;
    float s = 0.f;
#pragma unroll 8
    for (int k = 0; k < DH; ++k) s += hsh[k] * w[k];
    out[(size_t)b * DOUT + o] = s + b_fc[o];
}

extern "C" void kernel_launch(void* const* d_in, const int* in_sizes, int n_in,
                              void* d_out, int out_size, void* d_ws, size_t ws_size,
                              hipStream_t stream) {
    const float* x    = (const float*)d_in[0];
    const float* W_ih = (const float*)d_in[1];
    const float* W_hh = (const float*)d_in[2];
    const float* b_ih = (const float*)d_in[3];
    const float* b_hh = (const float*)d_in[4];
    const float* W_fc = (const float*)d_in[5];
    const float* b_fc = (const float*)d_in[6];
    float* out = (float*)d_out;

    char* base    = (char*)d_ws;
    u16*  xp      = (u16*)base;                                   // 256 MiB
    char* Wq      = base + (size_t)SEQ * BATCH * DH * 2;          // 256 KB int8 frags
    u16*  h_last  = (u16*)(Wq + (size_t)DH * DH);                 // 128 KB
    unsigned* wmx = (unsigned*)((char*)h_last + (size_t)BATCH * DH * 2);

    hipMemsetAsync(wmx, 0, sizeof(unsigned), stream);
    hipLaunchKernelGGL(wmax_kernel, dim3(256), dim3(256), 0, stream, W_hh, wmx);
    hipLaunchKernelGGL(pack_whh_i8_kernel, dim3(64), dim3(256), 0, stream, W_hh, wmx, Wq);
    hipLaunchKernelGGL(xproj_kernel, dim3(2048, 2), dim3(512), 0, stream, x, W_ih, b_ih, b_hh, xp);
    hipLaunchKernelGGL(rnn_rec_kernel, dim3(8), dim3(512), 0, stream, xp, Wq, wmx, h_last);
    hipLaunchKernelGGL(fc_kernel, dim3(128), dim3(256), 0, stream, h_last, W_fc, b_fc, out);
}

// Round 11
// 3336.848 us; speedup vs baseline: 5.1227x; 1.3835x over previous
//
#include <hip/hip_runtime.h>
#include <stdint.h>

#define SEQ   2048
#define BATCH 128
#define DIN   256
#define DH    512
#define DOUT  256

typedef uint16_t u16;
typedef uint32_t u32;
typedef __attribute__((ext_vector_type(8))) short short8;
typedef __attribute__((ext_vector_type(4))) float f32x4;
typedef __attribute__((ext_vector_type(4))) int i32x4;

__device__ __forceinline__ u16 f2bf(float f) {
    u32 u = __float_as_uint(f);
    u += 0x7fffu + ((u >> 16) & 1u);   // RNE
    return (u16)(u >> 16);
}
__device__ __forceinline__ float bf2f(u16 h) {
    return __uint_as_float(((u32)h) << 16);
}

// ---------------------------------------------------------------------------
// Pass A: max|W_hh| (for the int8 scale). 256 blocks x 256 thr x 4 elems.
// ---------------------------------------------------------------------------
__global__ __launch_bounds__(256) void wmax_kernel(const float* __restrict__ W,
                                                   unsigned* __restrict__ wmax) {
    __shared__ float red[256];
    int idx = blockIdx.x * 256 + threadIdx.x;
    float m = 0.f;
#pragma unroll
    for (int j = 0; j < 4; ++j) m = fmaxf(m, fabsf(W[(size_t)idx * 4 + j]));
    red[threadIdx.x] = m;
    __syncthreads();
    for (int s = 128; s > 0; s >>= 1) {
        if (threadIdx.x < s) red[threadIdx.x] = fmaxf(red[threadIdx.x], red[threadIdx.x + s]);
        __syncthreads();
    }
    if (threadIdx.x == 0) atomicMax(wmax, __float_as_uint(red[0]));  // floats >=0: uint order
}

// ---------------------------------------------------------------------------
// Pass B: pack W_hh into int8 MFMA-A-operand fragments.
// Wq[((wv*8+kc)*4+n)*1024 + lane*16 + j] =
//     rint( W[wv*64+n*16+(lane&15)][kc*64+(lane>>4)*16+j] * 127/wmax )
// ---------------------------------------------------------------------------
__global__ __launch_bounds__(256) void pack_whh_i8_kernel(
    const float* __restrict__ W, const unsigned* __restrict__ wmax,
    char* __restrict__ Wq) {
    int idx  = blockIdx.x * 256 + threadIdx.x;     // 0..16383
    int lane = idx & 63;
    int n    = (idx >> 6) & 3;
    int kc   = (idx >> 8) & 7;
    int wv   = idx >> 11;                           // 0..7
    float s = 127.0f / __uint_as_float(*wmax);
    int col = wv * 64 + n * 16 + (lane & 15);
    int k0  = kc * 64 + (lane >> 4) * 16;
    char q[16];
#pragma unroll
    for (int j = 0; j < 16; ++j)
        q[j] = (char)(int)rintf(W[(size_t)col * DH + k0 + j] * s);
    *reinterpret_cast<i32x4*>(Wq + (size_t)idx * 16) = *reinterpret_cast<i32x4*>(q);
}

// ---------------------------------------------------------------------------
// Phase 1: xp = 2*(x @ W_ih^T + b_ih + b_hh), bf16 (PRE-DOUBLED: the rec
// kernel's tanh needs exp(2*pre); folding the 2 here saves VALU per step).
// SWAPPED-OPERAND MFMA: lane holds 4 consecutive cols of one batch row.
// ---------------------------------------------------------------------------
__global__ __launch_bounds__(512) void xproj_kernel(
    const float* __restrict__ x, const float* __restrict__ W_ih,
    const float* __restrict__ b_ih, const float* __restrict__ b_hh,
    u16* __restrict__ xp) {
    __shared__ u16 As[128 * 64];
    __shared__ u16 Bs[256 * 64];
    const int tid  = threadIdx.x;
    const int lane = tid & 63;
    const int wid  = tid >> 6;     // 0..7
    const int wm   = wid >> 2;     // 0..1
    const int wn   = wid & 3;      // 0..3
    const int mt   = blockIdx.x;   // 0..2047
    const int nt   = blockIdx.y;   // 0..1

    f32x4 acc[4][4];
#pragma unroll
    for (int i = 0; i < 4; ++i)
#pragma unroll
        for (int j = 0; j < 4; ++j) acc[i][j] = (f32x4){0.f, 0.f, 0.f, 0.f};

    for (int kk = 0; kk < DIN; kk += 64) {
        __syncthreads();
        {   // stage A: 128 rows x 64 k (fp32 -> bf16), 16 elems/thread
            int r = tid >> 2, q = tid & 3;
            const float4* gp = (const float4*)(x + (size_t)(mt * 128 + r) * DIN + kk + q * 16);
            float4 v0 = gp[0], v1 = gp[1], v2 = gp[2], v3 = gp[3];
            short8 h0, h1;
            h0[0]=(short)f2bf(v0.x); h0[1]=(short)f2bf(v0.y); h0[2]=(short)f2bf(v0.z); h0[3]=(short)f2bf(v0.w);
            h0[4]=(short)f2bf(v1.x); h0[5]=(short)f2bf(v1.y); h0[6]=(short)f2bf(v1.z); h0[7]=(short)f2bf(v1.w);
            h1[0]=(short)f2bf(v2.x); h1[1]=(short)f2bf(v2.y); h1[2]=(short)f2bf(v2.z); h1[3]=(short)f2bf(v2.w);
            h1[4]=(short)f2bf(v3.x); h1[5]=(short)f2bf(v3.y); h1[6]=(short)f2bf(v3.z); h1[7]=(short)f2bf(v3.w);
            int base = r * 64, sw = (r & 7) << 3, ke = q * 16;
            *(short8*)&As[base + (ke ^ sw)]       = h0;
            *(short8*)&As[base + ((ke + 8) ^ sw)] = h1;
        }
        {   // stage B: 256 rows x 64 k, 32 elems/thread
            int r = tid >> 1, hf = tid & 1;
            const float4* gp = (const float4*)(W_ih + (size_t)(nt * 256 + r) * DIN + kk + hf * 32);
            int base = r * 64, sw = (r & 7) << 3;
#pragma unroll
            for (int cp = 0; cp < 2; ++cp) {
                float4 u0 = gp[cp*4+0], u1 = gp[cp*4+1], u2 = gp[cp*4+2], u3 = gp[cp*4+3];
                short8 t0, t1;
                t0[0]=(short)f2bf(u0.x); t0[1]=(short)f2bf(u0.y); t0[2]=(short)f2bf(u0.z); t0[3]=(short)f2bf(u0.w);
                t0[4]=(short)f2bf(u1.x); t0[5]=(short)f2bf(u1.y); t0[6]=(short)f2bf(u1.z); t0[7]=(short)f2bf(u1.w);
                t1[0]=(short)f2bf(u2.x); t1[1]=(short)f2bf(u2.y); t1[2]=(short)f2bf(u2.z); t1[3]=(short)f2bf(u2.w);
                t1[4]=(short)f2bf(u3.x); t1[5]=(short)f2bf(u3.y); t1[6]=(short)f2bf(u3.z); t1[7]=(short)f2bf(u3.w);
                int ke = hf * 32 + cp * 16;
                *(short8*)&Bs[base + (ke ^ sw)]       = t0;
                *(short8*)&Bs[base + ((ke + 8) ^ sw)] = t1;
            }
        }
        __syncthreads();
#pragma unroll
        for (int kt = 0; kt < 2; ++kt) {
            short8 a[4], b[4];
            int ke = kt * 32 + (lane >> 4) * 8;
#pragma unroll
            for (int mi = 0; mi < 4; ++mi) {
                int rr = wm * 64 + mi * 16 + (lane & 15);
                a[mi] = *(const short8*)&As[rr * 64 + (ke ^ ((rr & 7) << 3))];
            }
#pragma unroll
            for (int ni = 0; ni < 4; ++ni) {
                int rr = wn * 64 + ni * 16 + (lane & 15);
                b[ni] = *(const short8*)&Bs[rr * 64 + (ke ^ ((rr & 7) << 3))];
            }
            // SWAPPED: A-operand = W_ih frag, B-operand = x frag.
#pragma unroll
            for (int mi = 0; mi < 4; ++mi)
#pragma unroll
                for (int ni = 0; ni < 4; ++ni)
                    acc[mi][ni] = __builtin_amdgcn_mfma_f32_16x16x32_bf16(b[ni], a[mi], acc[mi][ni], 0, 0, 0);
        }
    }
    // epilogue: D row = W col = ni*16 + (lane>>4)*4 + r; D col = batch = lane&15.
    const int lq = lane >> 4;
#pragma unroll
    for (int ni = 0; ni < 4; ++ni) {
        int col0 = nt * 256 + wn * 64 + ni * 16 + lq * 4;
        float4 bi = *(const float4*)(b_ih + col0);
        float4 bh = *(const float4*)(b_hh + col0);
        float bb0 = bi.x + bh.x, bb1 = bi.y + bh.y, bb2 = bi.z + bh.z, bb3 = bi.w + bh.w;
#pragma unroll
        for (int mi = 0; mi < 4; ++mi) {
            float v0 = (acc[mi][ni][0] + bb0) * 2.0f;
            float v1 = (acc[mi][ni][1] + bb1) * 2.0f;
            float v2 = (acc[mi][ni][2] + bb2) * 2.0f;
            float v3 = (acc[mi][ni][3] + bb3) * 2.0f;
            uint2 v;
            v.x = (u32)f2bf(v0) | ((u32)f2bf(v1) << 16);
            v.y = (u32)f2bf(v2) | ((u32)f2bf(v3) << 16);
            int bbk = wm * 4 + mi;
            int cidx = (nt * 4 + wn) * 4 + ni;
            *(uint2*)(xp + ((((size_t)mt * 8 + bbk) * 32 + cidx) * 64 + lane) * 4) = v;
        }
    }
}

// ---------------------------------------------------------------------------
// Phase 2: recurrence, int8. 8 blocks x 512 thr (8 waves, 2/SIMD), 1 blk/CU.
// W_hh (256 KB int8): chunks 0..3 in LDS (128 KB), chunks 4..7 in REGISTERS
// (64 regs/wave), PINNED with "+v" redefinition asm. r10 lesson: at VGPR=88
// (budget 256) the compiler still sank the loop-invariant W loads — the
// sinking is a remat heuristic, not pressure. The pin makes the value's
// provenance the asm (not the load) -> remat illegal; demand ~152 < 256 ->
// no spill either. Per-step W traffic: ZERO.
// Epilogue folds: xp pre-doubled (xproj), tanh*127 = 127 - 254*rcp(e+1);
// h re-quantized to int8 for the next step; h_last bf16 at t=SEQ-1.
// ---------------------------------------------------------------------------
__global__ __launch_bounds__(512) void rnn_rec_kernel(
    const u16* __restrict__ xp, const char* __restrict__ Wq,
    const unsigned* __restrict__ wmax_p, u16* __restrict__ h_last) {
    __shared__ char W_lds[131072];        // 128 KB : chunks 0..3
    __shared__ char h_s[2][16 * 512];     // 16 KB  : int8 h double buffer
    const int tid = threadIdx.x, lane = tid & 63, wv = tid >> 6;  // wv 0..7
    const int bg = blockIdx.x;
    const int row = lane & 15, lq = lane >> 4;
    const int sw = (row & 7) << 4;
    // sc2 = wmax/127^2 * 2 (the 2 matches xp's pre-doubling)
    const float sc2 = __uint_as_float(*wmax_p) * (2.0f / (127.f * 127.f));

    // stage W chunks 0..3 into LDS (each wave its own 16 KB slice)
#pragma unroll
    for (int f = 0; f < 16; ++f) {
        int kc = f >> 2, n = f & 3;
        i32x4 v = *(const i32x4*)(Wq + (size_t)((wv * 8 + kc) * 4 + n) * 1024 + lane * 16);
        *(i32x4*)&W_lds[((wv * 4 + kc) * 4 + n) * 1024 + lane * 16] = v;
    }
    // chunks 4..7 -> registers, PINNED (see header comment)
    i32x4 wrr[4][4];
#pragma unroll
    for (int kc = 0; kc < 4; ++kc)
#pragma unroll
        for (int n = 0; n < 4; ++n) {
            wrr[kc][n] = *(const i32x4*)(Wq + (size_t)((wv * 8 + 4 + kc) * 4 + n) * 1024 + lane * 16);
            asm volatile("" : "+v"(wrr[kc][n]));
        }

    // h(0) = 0
    *(i32x4*)&h_s[0][tid * 32]      = (i32x4){0, 0, 0, 0};
    *(i32x4*)&h_s[0][tid * 32 + 16] = (i32x4){0, 0, 0, 0};

    // xp: strength-reduced running pointer (stride 65536 u16 per step)
    const u16* xpp = xp + (((size_t)(bg * 32 + wv * 4) * 64) + lane) * 4;
    uint2 xn[4];
#pragma unroll
    for (int n = 0; n < 4; ++n) xn[n] = *(const uint2*)(xpp + n * 256);
    xpp += 65536;

    __syncthreads();

    for (int t = 0; t < SEQ; ++t) {
        const int cur = t & 1, nxt = cur ^ 1;

        uint2 xc[4];
#pragma unroll
        for (int n = 0; n < 4; ++n) xc[n] = xn[n];
        // prefetch xp(t+1) EARLY: the compiler drains vmcnt(0) at the
        // barrier, so issue a full MFMA+epilogue phase ahead of the wait.
        if (t + 1 < SEQ) {
#pragma unroll
            for (int n = 0; n < 4; ++n) xn[n] = *(const uint2*)(xpp + n * 256);
            xpp += 65536;
        }

        i32x4 acc[4];
#pragma unroll
        for (int n = 0; n < 4; ++n) acc[n] = (i32x4){0, 0, 0, 0};

        // chunks 0..3 : W from LDS
#pragma unroll
        for (int kc = 0; kc < 4; ++kc) {
            i32x4 hf = *(const i32x4*)&h_s[cur][row * 512 + ((kc * 64 + lq * 16) ^ sw)];
#pragma unroll
            for (int n = 0; n < 4; ++n) {
                i32x4 wf = *(const i32x4*)&W_lds[((wv * 4 + kc) * 4 + n) * 1024 + lane * 16];
                acc[n] = __builtin_amdgcn_mfma_i32_16x16x64_i8(wf, hf, acc[n], 0, 0, 0);
            }
        }
        // chunks 4..7 : W from pinned registers
#pragma unroll
        for (int kc = 0; kc < 4; ++kc) {
            i32x4 hf = *(const i32x4*)&h_s[cur][row * 512 + (((kc + 4) * 64 + lq * 16) ^ sw)];
#pragma unroll
            for (int n = 0; n < 4; ++n)
                acc[n] = __builtin_amdgcn_mfma_i32_16x16x64_i8(wrr[kc][n], hf, acc[n], 0, 0, 0);
        }

        // epilogue: lane = (batch row = lane&15, cols colb..colb+3)
#pragma unroll
        for (int n = 0; n < 4; ++n) {
            float t0 = fmaf((float)acc[n][0], sc2, __uint_as_float(xc[n].x << 16));
            float t1 = fmaf((float)acc[n][1], sc2, __uint_as_float(xc[n].x & 0xffff0000u));
            float t2 = fmaf((float)acc[n][2], sc2, __uint_as_float(xc[n].y << 16));
            float t3 = fmaf((float)acc[n][3], sc2, __uint_as_float(xc[n].y & 0xffff0000u));
            // tanh(pre)*127 = 127 - 254 / (1 + exp(2*pre)); t? already = 2*pre
            float r0 = __builtin_amdgcn_rcpf(__expf(t0) + 1.0f);
            float r1 = __builtin_amdgcn_rcpf(__expf(t1) + 1.0f);
            float r2 = __builtin_amdgcn_rcpf(__expf(t2) + 1.0f);
            float r3 = __builtin_amdgcn_rcpf(__expf(t3) + 1.0f);
            float hq0 = fmaf(-254.f, r0, 127.f);
            float hq1 = fmaf(-254.f, r1, 127.f);
            float hq2 = fmaf(-254.f, r2, 127.f);
            float hq3 = fmaf(-254.f, r3, 127.f);
            int colb = wv * 64 + n * 16 + lq * 4;
            if (t == SEQ - 1) {
                uint2 hv;
                hv.x = (u32)f2bf(hq0 * (1.f / 127.f)) | ((u32)f2bf(hq1 * (1.f / 127.f)) << 16);
                hv.y = (u32)f2bf(hq2 * (1.f / 127.f)) | ((u32)f2bf(hq3 * (1.f / 127.f)) << 16);
                *(uint2*)(h_last + (size_t)(bg * 16 + row) * DH + colb) = hv;
            } else {
                int q0 = (int)rintf(hq0), q1 = (int)rintf(hq1);
                int q2 = (int)rintf(hq2), q3 = (int)rintf(hq3);
                u32 pk = (u32)(q0 & 255) | ((u32)(q1 & 255) << 8) |
                         ((u32)(q2 & 255) << 16) | ((u32)(q3 & 255) << 24);
                *(u32*)&h_s[nxt][row * 512 + (colb ^ sw)] = pk;
            }
        }
        if (t == SEQ - 1) break;
        __syncthreads();
    }
}

// ---------------------------------------------------------------------------
// Phase 3: out[b][o] = h_last[b,:]·W_fc[o,:] + b_fc[o]   (fp32 VALU, tiny)
// ---------------------------------------------------------------------------
__global__ __launch_bounds__(256) void fc_kernel(
    const u16* __restrict__ h_last, const float* __restrict__ W_fc,
    const float* __restrict__ b_fc, float* __restrict__ out) {
    __shared__ float hsh[DH];
    int b = blockIdx.x, o = threadIdx.x;
    for (int i = threadIdx.x; i < DH; i += 256) hsh[i] = bf2f(h_last[(size_t)b * DH + i]);
    __syncthreads();
    const float* w = W_fc + (size_t)o * DH;
    float s = 0.f;
#pragma unroll 8
    for (int k = 0; k < DH; ++k) s += hsh[k] * w[k];
    out[(size_t)b * DOUT + o] = s + b_fc[o];
}

extern "C" void kernel_launch(void* const* d_in, const int* in_sizes, int n_in,
                              void* d_out, int out_size, void* d_ws, size_t ws_size,
                              hipStream_t stream) {
    const float* x    = (const float*)d_in[0];
    const float* W_ih = (const float*)d_in[1];
    const float* W_hh = (const float*)d_in[2];
    const float* b_ih = (const float*)d_in[3];
    const float* b_hh = (const float*)d_in[4];
    const float* W_fc = (const float*)d_in[5];
    const float* b_fc = (const float*)d_in[6];
    float* out = (float*)d_out;

    char* base    = (char*)d_ws;
    u16*  xp      = (u16*)base;                                   // 256 MiB
    char* Wq      = base + (size_t)SEQ * BATCH * DH * 2;          // 256 KB int8 frags
    u16*  h_last  = (u16*)(Wq + (size_t)DH * DH);                 // 128 KB
    unsigned* wmx = (unsigned*)((char*)h_last + (size_t)BATCH * DH * 2);

    hipMemsetAsync(wmx, 0, sizeof(unsigned), stream);
    hipLaunchKernelGGL(wmax_kernel, dim3(256), dim3(256), 0, stream, W_hh, wmx);
    hipLaunchKernelGGL(pack_whh_i8_kernel, dim3(64), dim3(256), 0, stream, W_hh, wmx, Wq);
    hipLaunchKernelGGL(xproj_kernel, dim3(2048, 2), dim3(512), 0, stream, x, W_ih, b_ih, b_hh, xp);
    hipLaunchKernelGGL(rnn_rec_kernel, dim3(8), dim3(512), 0, stream, xp, Wq, wmx, h_last);
    hipLaunchKernelGGL(fc_kernel, dim3(128), dim3(256), 0, stream, h_last, W_fc, b_fc, out);
}

// Round 12
// 2824.744 us; speedup vs baseline: 6.0514x; 1.1813x over previous
//
#include <hip/hip_runtime.h>
#include <stdint.h>

#define SEQ   2048
#define BATCH 128
#define DIN   256
#define DH    512
#define DOUT  256

typedef uint16_t u16;
typedef uint32_t u32;
typedef __attribute__((ext_vector_type(8))) short short8;
typedef __attribute__((ext_vector_type(4))) float f32x4;
typedef __attribute__((ext_vector_type(4))) int i32x4;

__device__ __forceinline__ u16 f2bf(float f) {
    u32 u = __float_as_uint(f);
    u += 0x7fffu + ((u >> 16) & 1u);   // RNE
    return (u16)(u >> 16);
}
__device__ __forceinline__ float bf2f(u16 h) {
    return __uint_as_float(((u32)h) << 16);
}

// ---------------------------------------------------------------------------
// Pass A: max|W_hh| (for the int8 scale). 256 blocks x 256 thr x 4 elems.
// ---------------------------------------------------------------------------
__global__ __launch_bounds__(256) void wmax_kernel(const float* __restrict__ W,
                                                   unsigned* __restrict__ wmax) {
    __shared__ float red[256];
    int idx = blockIdx.x * 256 + threadIdx.x;
    float m = 0.f;
#pragma unroll
    for (int j = 0; j < 4; ++j) m = fmaxf(m, fabsf(W[(size_t)idx * 4 + j]));
    red[threadIdx.x] = m;
    __syncthreads();
    for (int s = 128; s > 0; s >>= 1) {
        if (threadIdx.x < s) red[threadIdx.x] = fmaxf(red[threadIdx.x], red[threadIdx.x + s]);
        __syncthreads();
    }
    if (threadIdx.x == 0) atomicMax(wmax, __float_as_uint(red[0]));  // floats >=0: uint order
}

// ---------------------------------------------------------------------------
// Pass B: pack W_hh into int8 MFMA-A-operand fragments.
// Wq[((wv*8+kc)*4+n)*1024 + lane*16 + j] =
//     rint( W[wv*64+n*16+(lane&15)][kc*64+(lane>>4)*16+j] * 127/wmax )
// ---------------------------------------------------------------------------
__global__ __launch_bounds__(256) void pack_whh_i8_kernel(
    const float* __restrict__ W, const unsigned* __restrict__ wmax,
    char* __restrict__ Wq) {
    int idx  = blockIdx.x * 256 + threadIdx.x;     // 0..16383
    int lane = idx & 63;
    int n    = (idx >> 6) & 3;
    int kc   = (idx >> 8) & 7;
    int wv   = idx >> 11;                           // 0..7
    float s = 127.0f / __uint_as_float(*wmax);
    int col = wv * 64 + n * 16 + (lane & 15);
    int k0  = kc * 64 + (lane >> 4) * 16;
    char q[16];
#pragma unroll
    for (int j = 0; j < 16; ++j)
        q[j] = (char)(int)rintf(W[(size_t)col * DH + k0 + j] * s);
    *reinterpret_cast<i32x4*>(Wq + (size_t)idx * 16) = *reinterpret_cast<i32x4*>(q);
}

// ---------------------------------------------------------------------------
// Phase 1: xp = 2*(x @ W_ih^T + b_ih + b_hh), bf16 (PRE-DOUBLED: the rec
// kernel's tanh needs exp(2*pre)). SWAPPED-OPERAND MFMA: lane holds 4
// consecutive cols of one batch row -> coalesced uint2 stores.
// ---------------------------------------------------------------------------
__global__ __launch_bounds__(512) void xproj_kernel(
    const float* __restrict__ x, const float* __restrict__ W_ih,
    const float* __restrict__ b_ih, const float* __restrict__ b_hh,
    u16* __restrict__ xp) {
    __shared__ u16 As[128 * 64];
    __shared__ u16 Bs[256 * 64];
    const int tid  = threadIdx.x;
    const int lane = tid & 63;
    const int wid  = tid >> 6;     // 0..7
    const int wm   = wid >> 2;     // 0..1
    const int wn   = wid & 3;      // 0..3
    const int mt   = blockIdx.x;   // 0..2047
    const int nt   = blockIdx.y;   // 0..1

    f32x4 acc[4][4];
#pragma unroll
    for (int i = 0; i < 4; ++i)
#pragma unroll
        for (int j = 0; j < 4; ++j) acc[i][j] = (f32x4){0.f, 0.f, 0.f, 0.f};

    for (int kk = 0; kk < DIN; kk += 64) {
        __syncthreads();
        {   // stage A: 128 rows x 64 k (fp32 -> bf16), 16 elems/thread
            int r = tid >> 2, q = tid & 3;
            const float4* gp = (const float4*)(x + (size_t)(mt * 128 + r) * DIN + kk + q * 16);
            float4 v0 = gp[0], v1 = gp[1], v2 = gp[2], v3 = gp[3];
            short8 h0, h1;
            h0[0]=(short)f2bf(v0.x); h0[1]=(short)f2bf(v0.y); h0[2]=(short)f2bf(v0.z); h0[3]=(short)f2bf(v0.w);
            h0[4]=(short)f2bf(v1.x); h0[5]=(short)f2bf(v1.y); h0[6]=(short)f2bf(v1.z); h0[7]=(short)f2bf(v1.w);
            h1[0]=(short)f2bf(v2.x); h1[1]=(short)f2bf(v2.y); h1[2]=(short)f2bf(v2.z); h1[3]=(short)f2bf(v2.w);
            h1[4]=(short)f2bf(v3.x); h1[5]=(short)f2bf(v3.y); h1[6]=(short)f2bf(v3.z); h1[7]=(short)f2bf(v3.w);
            int base = r * 64, sw = (r & 7) << 3, ke = q * 16;
            *(short8*)&As[base + (ke ^ sw)]       = h0;
            *(short8*)&As[base + ((ke + 8) ^ sw)] = h1;
        }
        {   // stage B: 256 rows x 64 k, 32 elems/thread
            int r = tid >> 1, hf = tid & 1;
            const float4* gp = (const float4*)(W_ih + (size_t)(nt * 256 + r) * DIN + kk + hf * 32);
            int base = r * 64, sw = (r & 7) << 3;
#pragma unroll
            for (int cp = 0; cp < 2; ++cp) {
                float4 u0 = gp[cp*4+0], u1 = gp[cp*4+1], u2 = gp[cp*4+2], u3 = gp[cp*4+3];
                short8 t0, t1;
                t0[0]=(short)f2bf(u0.x); t0[1]=(short)f2bf(u0.y); t0[2]=(short)f2bf(u0.z); t0[3]=(short)f2bf(u0.w);
                t0[4]=(short)f2bf(u1.x); t0[5]=(short)f2bf(u1.y); t0[6]=(short)f2bf(u1.z); t0[7]=(short)f2bf(u1.w);
                t1[0]=(short)f2bf(u2.x); t1[1]=(short)f2bf(u2.y); t1[2]=(short)f2bf(u2.z); t1[3]=(short)f2bf(u2.w);
                t1[4]=(short)f2bf(u3.x); t1[5]=(short)f2bf(u3.y); t1[6]=(short)f2bf(u3.z); t1[7]=(short)f2bf(u3.w);
                int ke = hf * 32 + cp * 16;
                *(short8*)&Bs[base + (ke ^ sw)]       = t0;
                *(short8*)&Bs[base + ((ke + 8) ^ sw)] = t1;
            }
        }
        __syncthreads();
#pragma unroll
        for (int kt = 0; kt < 2; ++kt) {
            short8 a[4], b[4];
            int ke = kt * 32 + (lane >> 4) * 8;
#pragma unroll
            for (int mi = 0; mi < 4; ++mi) {
                int rr = wm * 64 + mi * 16 + (lane & 15);
                a[mi] = *(const short8*)&As[rr * 64 + (ke ^ ((rr & 7) << 3))];
            }
#pragma unroll
            for (int ni = 0; ni < 4; ++ni) {
                int rr = wn * 64 + ni * 16 + (lane & 15);
                b[ni] = *(const short8*)&Bs[rr * 64 + (ke ^ ((rr & 7) << 3))];
            }
            // SWAPPED: A-operand = W_ih frag, B-operand = x frag.
#pragma unroll
            for (int mi = 0; mi < 4; ++mi)
#pragma unroll
                for (int ni = 0; ni < 4; ++ni)
                    acc[mi][ni] = __builtin_amdgcn_mfma_f32_16x16x32_bf16(b[ni], a[mi], acc[mi][ni], 0, 0, 0);
        }
    }
    // epilogue: D row = W col = ni*16 + (lane>>4)*4 + r; D col = batch = lane&15.
    const int lq = lane >> 4;
#pragma unroll
    for (int ni = 0; ni < 4; ++ni) {
        int col0 = nt * 256 + wn * 64 + ni * 16 + lq * 4;
        float4 bi = *(const float4*)(b_ih + col0);
        float4 bh = *(const float4*)(b_hh + col0);
        float bb0 = bi.x + bh.x, bb1 = bi.y + bh.y, bb2 = bi.z + bh.z, bb3 = bi.w + bh.w;
#pragma unroll
        for (int mi = 0; mi < 4; ++mi) {
            float v0 = (acc[mi][ni][0] + bb0) * 2.0f;
            float v1 = (acc[mi][ni][1] + bb1) * 2.0f;
            float v2 = (acc[mi][ni][2] + bb2) * 2.0f;
            float v3 = (acc[mi][ni][3] + bb3) * 2.0f;
            uint2 v;
            v.x = (u32)f2bf(v0) | ((u32)f2bf(v1) << 16);
            v.y = (u32)f2bf(v2) | ((u32)f2bf(v3) << 16);
            int bbk = wm * 4 + mi;
            int cidx = (nt * 4 + wn) * 4 + ni;
            *(uint2*)(xp + ((((size_t)mt * 8 + bbk) * 32 + cidx) * 64 + lane) * 4) = v;
        }
    }
}

// ---------------------------------------------------------------------------
// Phase 2: recurrence, int8. 8 blocks x 512 thr (8 waves, 2/SIMD), 1 blk/CU.
// ALL of W_hh (256 KB int8 = 32 frags = 128 regs/wave) lives in PINNED
// registers ("+v" redefinition asm; r10/r11: the pin is what stops the
// remat-by-default sinking; demand ~180 < 256 so no spill). Per-step W
// traffic: ZERO (no L2, no LDS). LDS holds only the 16 KB h double buffer.
// Epilogue: tanh*127 = 127 - 254*rcp(exp(2pre)+1) with xp pre-doubled;
// magic-constant fma (+1.5*2^23+127) gives RNE int8 in the float's low
// byte; v_perm_b32 x3 packs 4 bytes -> one b32 LDS write per n.
// ---------------------------------------------------------------------------
__global__ __launch_bounds__(512) void rnn_rec_kernel(
    const u16* __restrict__ xp, const char* __restrict__ Wq,
    const unsigned* __restrict__ wmax_p, u16* __restrict__ h_last) {
    __shared__ char h_s[2][16 * 512];     // 16 KB : int8 h double buffer
    const int tid = threadIdx.x, lane = tid & 63, wv = tid >> 6;  // wv 0..7
    const int bg = blockIdx.x;
    const int row = lane & 15, lq = lane >> 4;
    const int sw = (row & 7) << 4;
    // sc2 = wmax/127^2 * 2 (the 2 matches xp's pre-doubling)
    const float sc2 = __uint_as_float(*wmax_p) * (2.0f / (127.f * 127.f));

    // ALL W chunks 0..7 -> registers (32 x i32x4 = 128 regs), PINNED.
    i32x4 wrr[8][4];
#pragma unroll
    for (int kc = 0; kc < 8; ++kc)
#pragma unroll
        for (int n = 0; n < 4; ++n) {
            wrr[kc][n] = *(const i32x4*)(Wq + (size_t)((wv * 8 + kc) * 4 + n) * 1024 + lane * 16);
            asm volatile("" : "+v"(wrr[kc][n]));
        }

    // h(0) = 0 (both parity buffers, 16 KB via flat 32 B/thread)
    *(i32x4*)&h_s[0][tid * 32]      = (i32x4){0, 0, 0, 0};
    *(i32x4*)&h_s[0][tid * 32 + 16] = (i32x4){0, 0, 0, 0};

    // xp: strength-reduced running pointer (stride 65536 u16 per step)
    const u16* xpp = xp + (((size_t)(bg * 32 + wv * 4) * 64) + lane) * 4;
    uint2 xn[4];
#pragma unroll
    for (int n = 0; n < 4; ++n) xn[n] = *(const uint2*)(xpp + n * 256);
    xpp += 65536;

    __syncthreads();

    for (int t = 0; t < SEQ; ++t) {
        const int cur = t & 1, nxt = cur ^ 1;

        uint2 xc[4];
#pragma unroll
        for (int n = 0; n < 4; ++n) xc[n] = xn[n];
        // prefetch xp(t+1) EARLY (a full MFMA+epilogue phase ahead of use)
        if (t + 1 < SEQ) {
#pragma unroll
            for (int n = 0; n < 4; ++n) xn[n] = *(const uint2*)(xpp + n * 256);
            xpp += 65536;
        }

        i32x4 acc[4];
#pragma unroll
        for (int n = 0; n < 4; ++n) acc[n] = (i32x4){0, 0, 0, 0};

        // all 8 chunks: W from pinned registers, h from LDS (8 b128 reads)
#pragma unroll
        for (int kc = 0; kc < 8; ++kc) {
            i32x4 hf = *(const i32x4*)&h_s[cur][row * 512 + ((kc * 64 + lq * 16) ^ sw)];
#pragma unroll
            for (int n = 0; n < 4; ++n)
                acc[n] = __builtin_amdgcn_mfma_i32_16x16x64_i8(wrr[kc][n], hf, acc[n], 0, 0, 0);
        }

        // epilogue: lane = (batch row = lane&15, cols colb..colb+3)
#pragma unroll
        for (int n = 0; n < 4; ++n) {
            float t0 = fmaf((float)acc[n][0], sc2, __uint_as_float(xc[n].x << 16));
            float t1 = fmaf((float)acc[n][1], sc2, __uint_as_float(xc[n].x & 0xffff0000u));
            float t2 = fmaf((float)acc[n][2], sc2, __uint_as_float(xc[n].y << 16));
            float t3 = fmaf((float)acc[n][3], sc2, __uint_as_float(xc[n].y & 0xffff0000u));
            // r = 1/(1+exp(2*pre));  tanh(pre) = 1 - 2r
            float r0 = __builtin_amdgcn_rcpf(__expf(t0) + 1.0f);
            float r1 = __builtin_amdgcn_rcpf(__expf(t1) + 1.0f);
            float r2 = __builtin_amdgcn_rcpf(__expf(t2) + 1.0f);
            float r3 = __builtin_amdgcn_rcpf(__expf(t3) + 1.0f);
            int colb = wv * 64 + n * 16 + lq * 4;
            if (t == SEQ - 1) {
                float h0 = fmaf(-2.f, r0, 1.f), h1 = fmaf(-2.f, r1, 1.f);
                float h2 = fmaf(-2.f, r2, 1.f), h3 = fmaf(-2.f, r3, 1.f);
                uint2 hv;
                hv.x = (u32)f2bf(h0) | ((u32)f2bf(h1) << 16);
                hv.y = (u32)f2bf(h2) | ((u32)f2bf(h3) << 16);
                *(uint2*)(h_last + (size_t)(bg * 16 + row) * DH + colb) = hv;
            } else {
                // magic-constant RNE: fma(-254, r, 127 + 1.5*2^23) puts the
                // rounded int8 (two's complement) in the float's low byte.
                u32 b0 = __float_as_uint(fmaf(-254.f, r0, 12583039.f));
                u32 b1 = __float_as_uint(fmaf(-254.f, r1, 12583039.f));
                u32 b2 = __float_as_uint(fmaf(-254.f, r2, 12583039.f));
                u32 b3 = __float_as_uint(fmaf(-254.f, r3, 12583039.f));
                u32 p01 = __builtin_amdgcn_perm(b1, b0, 0x00000400u);  // (b0.lo, b1.lo)
                u32 p23 = __builtin_amdgcn_perm(b3, b2, 0x00000400u);  // (b2.lo, b3.lo)
                u32 pk  = __builtin_amdgcn_perm(p23, p01, 0x05040100u);
                *(u32*)&h_s[nxt][row * 512 + (colb ^ sw)] = pk;
            }
        }
        if (t == SEQ - 1) break;
        __syncthreads();
    }
}

// ---------------------------------------------------------------------------
// Phase 3: out[b][o] = h_last[b,:]·W_fc[o,:] + b_fc[o]   (fp32 VALU, tiny)
// ---------------------------------------------------------------------------
__global__ __launch_bounds__(256) void fc_kernel(
    const u16* __restrict__ h_last, const float* __restrict__ W_fc,
    const float* __restrict__ b_fc, float* __restrict__ out) {
    __shared__ float hsh[DH];
    int b = blockIdx.x, o = threadIdx.x;
    for (int i = threadIdx.x; i < DH; i += 256) hsh[i] = bf2f(h_last[(size_t)b * DH + i]);
    __syncthreads();
    const float* w = W_fc + (size_t)o * DH;
    float s = 0.f;
#pragma unroll 8
    for (int k = 0; k < DH; ++k) s += hsh[k] * w[k];
    out[(size_t)b * DOUT + o] = s + b_fc[o];
}

extern "C" void kernel_launch(void* const* d_in, const int* in_sizes, int n_in,
                              void* d_out, int out_size, void* d_ws, size_t ws_size,
                              hipStream_t stream) {
    const float* x    = (const float*)d_in[0];
    const float* W_ih = (const float*)d_in[1];
    const float* W_hh = (const float*)d_in[2];
    const float* b_ih = (const float*)d_in[3];
    const float* b_hh = (const float*)d_in[4];
    const float* W_fc = (const float*)d_in[5];
    const float* b_fc = (const float*)d_in[6];
    float* out = (float*)d_out;

    char* base    = (char*)d_ws;
    u16*  xp      = (u16*)base;                                   // 256 MiB
    char* Wq      = base + (size_t)SEQ * BATCH * DH * 2;          // 256 KB int8 frags
    u16*  h_last  = (u16*)(Wq + (size_t)DH * DH);                 // 128 KB
    unsigned* wmx = (unsigned*)((char*)h_last + (size_t)BATCH * DH * 2);

    hipMemsetAsync(wmx, 0, sizeof(unsigned), stream);
    hipLaunchKernelGGL(wmax_kernel, dim3(256), dim3(256), 0, stream, W_hh, wmx);
    hipLaunchKernelGGL(pack_whh_i8_kernel, dim3(64), dim3(256), 0, stream, W_hh, wmx, Wq);
    hipLaunchKernelGGL(xproj_kernel, dim3(2048, 2), dim3(512), 0, stream, x, W_ih, b_ih, b_hh, xp);
    hipLaunchKernelGGL(rnn_rec_kernel, dim3(8), dim3(512), 0, stream, xp, Wq, wmx, h_last);
    hipLaunchKernelGGL(fc_kernel, dim3(128), dim3(256), 0, stream, h_last, W_fc, b_fc, out);
}